// Round 1
// baseline (65480.066 us; speedup 1.0000x reference)
//
#include <hip/hip_runtime.h>

// ---------------------------------------------------------------------------
// HiPPO-LSTM, B=32, S=2048, D=512, H=512, N=256, G=2048.
//
// Fully-fused sequential kernel (64 persistent blocks, 1 device barrier/step):
//   gates = x_t·Wx^T + h·Whh^T + hippo·Wn^T   (all via bf16 MFMA, split ops:
//     x,h paths: hi/lo Ootomo 3-pass; hippo path: hi/mid/lo 6-pass)
//   elementwise LSTM in fp64; S_f[b] = h·wbar + beta in fp64
//   barrier; closed-form fp64 hippo update (fp64 hippo state in registers).
//
// R4 changes (latency regime — MfmaUtil 0.85%, VALUBusy 2.4%, all stall):
//   * NO __threadfence: cross-block data (HB2 h-exchange, SfP) uses
//     device-coherent relaxed atomics (sc1, bypasses non-coherent L2);
//     barrier arrival is a RELEASE fetch_add. WREC/X stay L2-resident
//     across steps instead of being invalidated every step.
//   * h-exchange staged into LDS in one cooperative pass (one L3 latency
//     exposure instead of 16 serialized ones in the MFMA loop).
//     h packed as uint (hi-bf16 | lo-bf16<<16). hippo fp64 state moved
//     from LDS to registers (hn[32]/thread) to free the 64KB.
//   * x-path MFMA for t+1 computed between barrier arrival and spin
//     (hidden under barrier wait; its streaming loads prefetch there too).
//   * out[] written with nontemporal stores (stop thrashing L3/L2).
// ---------------------------------------------------------------------------

#define B_ 32
#define S_ 2048
#define D_ 512
#define H_ 512
#define NH_ 256
#define G_ 2048
#define KW 2816          // WREC row: hh_hi 512|hh_lo 512|xw_hi 512|xw_lo 512|nw_hi 256|nw_mid 256|nw_lo 256
#define NBLK 64
#define JPB 8
#define MAXS 1000.0

typedef __attribute__((ext_vector_type(8))) short short8;
typedef __attribute__((ext_vector_type(4))) float f32x4;
typedef __attribute__((ext_vector_type(4))) unsigned int uint4v;

// ws layout (bytes)
#define CNT_OFF   0ULL
#define SFP_OFF   256ULL                       // double[2][64][32] = 32768
#define HB_OFF    33024ULL                     // uint[2][32][512] = 131072 (hi|lo packed)
#define STATE_BYTES 164096ULL
#define XBH_OFF   164096ULL                    // ushort[32][2048][512] = 67108864
#define XBL_OFF   67272960ULL                  // ushort[32][2048][512] = 67108864
#define WREC_OFF  134381824ULL                 // ushort[2048][2816] = 11534336

__device__ __forceinline__ unsigned short f2b(float f) {
  unsigned u = __float_as_uint(f);
  unsigned r = (u + 0x7fffu + ((u >> 16) & 1u)) >> 16;
  return (unsigned short)r;
}
__device__ __forceinline__ float b2f(unsigned short s) {
  return __uint_as_float(((unsigned)s) << 16);
}
__device__ __forceinline__ double sigm_d(double x) { return 1.0 / (1.0 + exp(-x)); }
__device__ __forceinline__ double tanh_d(double x) {
  double e = exp(2.0 * x);
  return isinf(e) ? 1.0 : (1.0 - 2.0 / (e + 1.0));
}

// unpack 8 packed uints (hi-bf16 in low16, lo-bf16 in high16) into two short8
__device__ __forceinline__ void unpack8(const unsigned* p, short8& hi, short8& lo) {
  uint4v a = *(const uint4v*)p;
  uint4v b = *(const uint4v*)(p + 4);
  hi[0] = (short)a.x; lo[0] = (short)(a.x >> 16);
  hi[1] = (short)a.y; lo[1] = (short)(a.y >> 16);
  hi[2] = (short)a.z; lo[2] = (short)(a.z >> 16);
  hi[3] = (short)a.w; lo[3] = (short)(a.w >> 16);
  hi[4] = (short)b.x; lo[4] = (short)(b.x >> 16);
  hi[5] = (short)b.y; lo[5] = (short)(b.y >> 16);
  hi[6] = (short)b.z; lo[6] = (short)(b.z >> 16);
  hi[7] = (short)b.w; lo[7] = (short)(b.w >> 16);
}

// ---------------- prep kernels ----------------
__global__ __launch_bounds__(256) void k_cvt2(const float* __restrict__ in,
                                              unsigned short* __restrict__ hi,
                                              unsigned short* __restrict__ lo, size_t n) {
  size_t i = (size_t)blockIdx.x * blockDim.x + threadIdx.x;
  size_t stride = (size_t)gridDim.x * blockDim.x;
  for (; i < n; i += stride) {
    float v = in[i];
    unsigned short h = f2b(v);
    hi[i] = h;
    lo[i] = f2b(v - b2f(h));
  }
}

__global__ __launch_bounds__(256) void k_wrec2(const float* __restrict__ Whh,
                                               const float* __restrict__ Wih,
                                               unsigned short* __restrict__ out) {
  size_t i = (size_t)blockIdx.x * 256 + threadIdx.x;   // over 2048*2816
  if (i >= (size_t)G_ * KW) return;
  int gb = (int)(i / KW), k = (int)(i % KW);
  int blk = gb >> 5, c = gb & 31;
  int grow = (c >> 3) * H_ + blk * JPB + (c & 7);      // gate*512 + hidden index
  unsigned short v;
  if (k < 512) {                                        // Whh hi
    v = f2b(Whh[(size_t)grow * 512 + k]);
  } else if (k < 1024) {                                // Whh lo
    float w = Whh[(size_t)grow * 512 + (k - 512)];
    v = f2b(w - b2f(f2b(w)));
  } else if (k < 1536) {                                // Wih-x hi
    v = f2b(Wih[(size_t)grow * 768 + (k - 1024)]);
  } else if (k < 2048) {                                // Wih-x lo
    float w = Wih[(size_t)grow * 768 + (k - 1536)];
    v = f2b(w - b2f(f2b(w)));
  } else if (k < 2304) {                                // Wih-hippo hi
    v = f2b(Wih[(size_t)grow * 768 + 512 + (k - 2048)]);
  } else if (k < 2560) {                                // Wih-hippo mid
    float w = Wih[(size_t)grow * 768 + 512 + (k - 2304)];
    v = f2b(w - b2f(f2b(w)));
  } else {                                              // Wih-hippo lo
    float w = Wih[(size_t)grow * 768 + 512 + (k - 2560)];
    float h1 = b2f(f2b(w));
    float m1 = b2f(f2b(w - h1));
    v = f2b(w - h1 - m1);
  }
  out[i] = v;
}

// ---------------- persistent sequential kernel ----------------
__global__ __launch_bounds__(256, 1) void k_seq(const unsigned short* __restrict__ XBH,
                                                const unsigned short* __restrict__ XBL,
                                                const unsigned short* __restrict__ WREC,
                                                const float* __restrict__ Wh2h,
                                                const float* __restrict__ bh2h,
                                                const float* __restrict__ bih,
                                                const float* __restrict__ bhh,
                                                float* __restrict__ out,
                                                unsigned* __restrict__ HB2,
                                                double* __restrict__ SfP,
                                                unsigned* __restrict__ cnt) {
  const int blk = blockIdx.x, tid = threadIdx.x;

  __shared__ unsigned hlds[32][516];           // staged h(t-1): hi|lo packed, +4 pad (2-way banks)
  __shared__ unsigned short hip_hi[32][264];   // bf16 hi/mid/lo for MFMA A-frags
  __shared__ unsigned short hip_mi[32][264];
  __shared__ unsigned short hip_lo[32][264];
  __shared__ float gat_xh[32][33];             // x+h MFMA partial
  __shared__ float gat_n[32][33];              // hippo MFMA partial
  __shared__ double cst[32][JPB];              // cell state fp64
  __shared__ double segw[32][8], segu[32][8];
  __shared__ double sfl[32];
  __shared__ double wbar[JPB];
  __shared__ double stabd[256];
  __shared__ double sbeta;

  for (int i = tid; i < 32 * 516; i += 256) (&hlds[0][0])[i] = 0u;
  for (int i = tid; i < 32 * 264; i += 256) {
    (&hip_hi[0][0])[i] = 0; (&hip_mi[0][0])[i] = 0; (&hip_lo[0][0])[i] = 0;
  }
  for (int i = tid; i < 32 * JPB; i += 256) (&cst[0][0])[i] = 0.0;
  stabd[tid] = sqrt(2.0 * (double)tid + 1.0);
  if (tid < JPB) {
    double s = 0.0;
    for (int n = 0; n < NH_; ++n) s += (double)Wh2h[(size_t)n * H_ + blk * JPB + tid];
    wbar[tid] = s;
  }
  if (tid == 0) {
    double s = 0.0;
    for (int n = 0; n < NH_; ++n) s += (double)bh2h[n];
    sbeta = s;
  }

  // fp64 hippo state in registers: thread (hb,hs) owns n = hs*32 .. hs*32+31 of batch hb
  double hn[32];
#pragma unroll
  for (int i = 0; i < 32; ++i) hn[i] = 0.0;
  __syncthreads();

  // MFMA roles (4 waves)
  const int w = tid >> 6, l = tid & 63;
  const int lb = l & 15, lq = l >> 4;
  const int mt = w & 1, nt = w >> 1;
  const int bA = mt * 16 + lb;         // batch row for A frags
  const int cB = nt * 16 + lb;         // local gate col for B frags
  const unsigned short* wrow = WREC + ((size_t)(blk * 32 + cB)) * KW + lq * 8;
  // elementwise roles
  const int eb = tid >> 3, ej = tid & 7;
  const int jg = blk * JPB + ej;
  // per-thread gate biases (fp64)
  const double bi0 = (double)bih[0 * 512 + jg] + (double)bhh[0 * 512 + jg];
  const double bi1 = (double)bih[1 * 512 + jg] + (double)bhh[1 * 512 + jg];
  const double bi2 = (double)bih[2 * 512 + jg] + (double)bhh[2 * 512 + jg];
  const double bi3 = (double)bih[3 * 512 + jg] + (double)bhh[3 * 512 + jg];
  // hippo-scan roles
  const int hb = tid & 31, hs = tid >> 5;

  // x-path MFMA (Ootomo 3-pass, K=512); runs under the barrier wait for t+1
  auto xpass = [&](int tt) -> f32x4 {
    f32x4 a = {0.f, 0.f, 0.f, 0.f};
    const unsigned short* xh = XBH + ((size_t)bA * S_ + tt) * D_ + lq * 8;
    const unsigned short* xl = XBL + ((size_t)bA * S_ + tt) * D_ + lq * 8;
#pragma unroll
    for (int kt = 0; kt < 16; ++kt) {
      short8 ah = *(const short8*)(xh + kt * 32);
      short8 al = *(const short8*)(xl + kt * 32);
      short8 bh = *(const short8*)(wrow + 1024 + kt * 32);
      short8 bl = *(const short8*)(wrow + 1536 + kt * 32);
      a = __builtin_amdgcn_mfma_f32_16x16x32_bf16(ah, bh, a, 0, 0, 0);
      a = __builtin_amdgcn_mfma_f32_16x16x32_bf16(ah, bl, a, 0, 0, 0);
      a = __builtin_amdgcn_mfma_f32_16x16x32_bf16(al, bh, a, 0, 0, 0);
    }
    return a;
  };
  f32x4 axx = xpass(0);   // prologue: x-path for t=0

  for (int t = 0; t < S_; ++t) {
    const int wslot = t & 1;

    // ---- phase B: gates MFMA for step t ----
    // hippo path: hi/mid/lo x hi/mid/lo, 6 passes, K=256 (separate accumulator)
    f32x4 an = {0.f, 0.f, 0.f, 0.f};
#pragma unroll
    for (int kt = 0; kt < 8; ++kt) {
      short8 ah = *(const short8*)(&hip_hi[bA][kt * 32 + lq * 8]);
      short8 am = *(const short8*)(&hip_mi[bA][kt * 32 + lq * 8]);
      short8 al = *(const short8*)(&hip_lo[bA][kt * 32 + lq * 8]);
      short8 bh = *(const short8*)(wrow + 2048 + kt * 32);
      short8 bm = *(const short8*)(wrow + 2304 + kt * 32);
      short8 bl = *(const short8*)(wrow + 2560 + kt * 32);
      an = __builtin_amdgcn_mfma_f32_16x16x32_bf16(ah, bh, an, 0, 0, 0);
      an = __builtin_amdgcn_mfma_f32_16x16x32_bf16(ah, bm, an, 0, 0, 0);
      an = __builtin_amdgcn_mfma_f32_16x16x32_bf16(am, bh, an, 0, 0, 0);
      an = __builtin_amdgcn_mfma_f32_16x16x32_bf16(ah, bl, an, 0, 0, 0);
      an = __builtin_amdgcn_mfma_f32_16x16x32_bf16(am, bm, an, 0, 0, 0);
      an = __builtin_amdgcn_mfma_f32_16x16x32_bf16(al, bh, an, 0, 0, 0);
    }
    // h path: hi/lo Ootomo 3-pass, K=512, from LDS stage (chained onto x accum)
    f32x4 axh = axx;
    const unsigned* hrow = &hlds[bA][lq * 8];
#pragma unroll
    for (int kt = 0; kt < 16; ++kt) {
      short8 ah, al;
      unpack8(hrow + kt * 32, ah, al);
      short8 bh = *(const short8*)(wrow + kt * 32);
      short8 bl = *(const short8*)(wrow + 512 + kt * 32);
      axh = __builtin_amdgcn_mfma_f32_16x16x32_bf16(ah, bh, axh, 0, 0, 0);
      axh = __builtin_amdgcn_mfma_f32_16x16x32_bf16(ah, bl, axh, 0, 0, 0);
      axh = __builtin_amdgcn_mfma_f32_16x16x32_bf16(al, bh, axh, 0, 0, 0);
    }
#pragma unroll
    for (int r = 0; r < 4; ++r) {
      gat_xh[mt * 16 + lq * 4 + r][cB] = axh[r];
      gat_n[mt * 16 + lq * 4 + r][cB] = an[r];
    }
    __syncthreads();

    // ---- phase C: elementwise LSTM (fp64) ----
    {
      double pi = (double)gat_xh[eb][0 * 8 + ej] + (double)gat_n[eb][0 * 8 + ej] + bi0;
      double pf = (double)gat_xh[eb][1 * 8 + ej] + (double)gat_n[eb][1 * 8 + ej] + bi1;
      double pg = (double)gat_xh[eb][2 * 8 + ej] + (double)gat_n[eb][2 * 8 + ej] + bi2;
      double po = (double)gat_xh[eb][3 * 8 + ej] + (double)gat_n[eb][3 * 8 + ej] + bi3;
      double c = sigm_d(pf) * cst[eb][ej] + sigm_d(pi) * tanh_d(pg);
      cst[eb][ej] = c;
      double h = sigm_d(po) * tanh_d(c);
      size_t oidx = (size_t)eb * (S_ * H_) + (size_t)t * H_ + jg;
      __builtin_nontemporal_store((float)h, &out[oidx]);
      __builtin_nontemporal_store((float)c, &out[(size_t)B_ * S_ * H_ + oidx]);
      float hf = (float)h;
      unsigned short hh = f2b(hf);
      unsigned short hl = f2b((float)(h - (double)b2f(hh)));
      unsigned hv = (unsigned)hh | ((unsigned)hl << 16);
      __hip_atomic_store(HB2 + (size_t)wslot * (B_ * H_) + (size_t)eb * H_ + jg, hv,
                         __ATOMIC_RELAXED, __HIP_MEMORY_SCOPE_AGENT);
      // partial S_f (fp64)
      double part = h * wbar[ej];
      part += __shfl_down(part, 4, 64);
      part += __shfl_down(part, 2, 64);
      part += __shfl_down(part, 1, 64);
      if (ej == 0)
        __hip_atomic_store(SfP + (size_t)wslot * (NBLK * B_) + blk * B_ + eb, part,
                           __ATOMIC_RELAXED, __HIP_MEMORY_SCOPE_AGENT);
    }
    __syncthreads();   // per-wave vmcnt(0) drain at barrier: all sc1 stores at L3

    if (t == S_ - 1) break;

    // -------- device barrier (no threadfence: exchange data is sc1-coherent) --------
    if (tid == 0)
      __hip_atomic_fetch_add(cnt, 1u, __ATOMIC_RELEASE, __HIP_MEMORY_SCOPE_AGENT);

    // ---- phase D: x-path MFMA for t+1, hidden under the barrier wait ----
    axx = xpass(t + 1);

    if (tid == 0) {
      const unsigned target = (unsigned)NBLK * (unsigned)(t + 1);
      while (__hip_atomic_load(cnt, __ATOMIC_RELAXED, __HIP_MEMORY_SCOPE_AGENT) < target) {}
    }
    __syncthreads();

    // ---- phase A: exchange + hippo segment sums ----
    {
      // issue SfP loads first (needed soonest)
      double acc[8];
      double* sp = SfP + (size_t)wslot * (NBLK * B_) + eb;
#pragma unroll
      for (int m = 0; m < 8; ++m)
        acc[m] = __hip_atomic_load(sp + (size_t)(ej * 8 + m) * B_,
                                   __ATOMIC_RELAXED, __HIP_MEMORY_SCOPE_AGENT);

      // hippo segment sums from register state (overlaps load latency)
      double sw = 0.0, su = 0.0;
#pragma unroll
      for (int i = 0; i < 32; ++i) {
        double hv = hn[i];
        sw += stabd[hs * 32 + i] * hv;
        su += hv;
      }
      segw[hb][hs] = sw;
      segu[hb][hs] = su;

      // stage h(t) plane (64KB) into LDS: 64 coherent dword loads/thread, pipelined
      unsigned* hbsrc = HB2 + (size_t)wslot * (B_ * H_);
      unsigned* hflat = &hlds[0][0];
#pragma unroll
      for (int m = 0; m < 64; ++m) {
        const int fi = (m << 8) + tid;
        unsigned v = __hip_atomic_load(hbsrc + fi, __ATOMIC_RELAXED, __HIP_MEMORY_SCOPE_AGENT);
        hflat[(fi >> 9) * 516 + (fi & 511)] = v;
      }

      // S_f reduce (order-preserving)
      double v = 0.0;
#pragma unroll
      for (int m = 0; m < 8; ++m) v += acc[m];
      v += __shfl_down(v, 4, 64);
      v += __shfl_down(v, 2, 64);
      v += __shfl_down(v, 1, 64);
      if (ej == 0) sfl[eb] = v + sbeta;
    }
    __syncthreads();

    // hippo closed-form update in fp64 (register state, deterministic)
    {
      double U = 0.0, Sh = 0.0;
#pragma unroll
      for (int s2 = 0; s2 < 8; ++s2) {
        Sh += segu[hb][s2];
        if (s2 < hs) U += segw[hb][s2];
      }
      const double Sf = sfl[hb];
      const double inv = 0.5 / (double)(t + 1);
#pragma unroll
      for (int i = 0; i < 32; ++i) {
        const int n = hs * 32 + i;
        double hv = hn[i];
        double vv = Sh + inv * (stabd[n] * (Sf - U) - (double)(n + 1) * hv);
        vv = fmin(fmax(vv, -MAXS), MAXS);
        hn[i] = vv;
        unsigned short vh = f2b((float)vv);
        double rem = vv - (double)b2f(vh);
        unsigned short vm = f2b((float)rem);
        rem -= (double)b2f(vm);
        hip_hi[hb][n] = vh;
        hip_mi[hb][n] = vm;
        hip_lo[hb][n] = f2b((float)rem);
        U += stabd[n] * hv;
      }
    }
    __syncthreads();
  }
}

extern "C" void kernel_launch(void* const* d_in, const int* in_sizes, int n_in,
                              void* d_out, int out_size, void* d_ws, size_t ws_size,
                              hipStream_t stream) {
  const float* x    = (const float*)d_in[0];
  const float* Wih  = (const float*)d_in[1];
  const float* Whh  = (const float*)d_in[2];
  const float* bih  = (const float*)d_in[3];
  const float* bhh  = (const float*)d_in[4];
  const float* Wh2h = (const float*)d_in[5];
  const float* bh2h = (const float*)d_in[6];
  float* out = (float*)d_out;
  char* ws = (char*)d_ws;

  unsigned* cnt        = (unsigned*)(ws + CNT_OFF);
  double* SfP          = (double*)(ws + SFP_OFF);
  unsigned* HB2        = (unsigned*)(ws + HB_OFF);
  unsigned short* XBH  = (unsigned short*)(ws + XBH_OFF);
  unsigned short* XBL  = (unsigned short*)(ws + XBL_OFF);
  unsigned short* WREC = (unsigned short*)(ws + WREC_OFF);

  hipMemsetAsync(ws, 0, STATE_BYTES, stream);
  k_cvt2<<<8192, 256, 0, stream>>>(x, XBH, XBL, (size_t)B_ * S_ * D_);
  k_wrec2<<<((size_t)G_ * KW + 255) / 256, 256, 0, stream>>>(Whh, Wih, WREC);
  k_seq<<<NBLK, 256, 0, stream>>>(XBH, XBL, WREC, Wh2h, bh2h, bih, bhh, out, HB2, SfP, cnt);
}

// Round 2
// 52225.189 us; speedup vs baseline: 1.2538x; 1.2538x over previous
//
#include <hip/hip_runtime.h>

// ---------------------------------------------------------------------------
// HiPPO-LSTM, B=32, S=2048, D=512, H=512, N=256, G=2048.
//
// Fully-fused sequential kernel (64 persistent blocks, 1 device barrier/step):
//   gates = x_t·Wx^T + h·Whh^T + hippo·Wn^T   (all via bf16 MFMA, split ops:
//     x,h paths: hi/lo Ootomo 3-pass; hippo path: hi/mid/lo 6-pass)
//   elementwise LSTM in fp64 (c in LDS fp64, double exp)
//   S_f[b] = h·wbar + beta in fp64
//   barrier; closed-form fp64 hippo update.
//
// R5 (revert R1's sc1 exchange — it regressed; FETCH unchanged proved the
// 1.2GB fetch is structural x-streaming per XCD, not fence invalidation):
//   * Exchange is back to R0's proven plain-store + release-wbl2 +
//     acquire-inv pattern (L2-visible, fast).
//   * Barrier: single-counter fetch_add (64 serialized RMWs + 64 pollers
//     on ONE L3 line = saturated line queue) replaced by per-block arrival
//     flags in separate 256B-strided lines + wave-0 PARALLEL poll (lane i
//     polls flag i, one ~700cy wave-load round per check). No RMWs.
//   * x-path MFMA for t+1 computed between arrival store and poll
//     (hidden under barrier wait; arrival precedes it -> adds no skew).
//   * Hippo-path B-fragments (loop-invariant WREC reads) hoisted into
//     registers once for all 2048 steps (24 short8 = 96 VGPR): removes
//     24 post-inv L3 loads from the post-barrier critical path.
// ---------------------------------------------------------------------------

#define B_ 32
#define S_ 2048
#define D_ 512
#define H_ 512
#define NH_ 256
#define G_ 2048
#define KW 2816          // WREC row: hh_hi 512|hh_lo 512|xw_hi 512|xw_lo 512|nw_hi 256|nw_mid 256|nw_lo 256
#define NBLK 64
#define JPB 8
#define MAXS 1000.0

typedef __attribute__((ext_vector_type(8))) short short8;
typedef __attribute__((ext_vector_type(4))) float f32x4;

// ws layout (bytes)
#define CNT_OFF   0ULL
#define SFP_OFF   256ULL                       // double[2][64][32] = 32768
#define HB_OFF    33024ULL                     // ushort[2][32][1024] = 131072 (hi|lo planes)
#define STATE_BYTES 164096ULL
#define XBH_OFF   164096ULL                    // ushort[32][2048][512] = 67108864
#define XBL_OFF   67272960ULL                  // ushort[32][2048][512] = 67108864
#define WREC_OFF  134381824ULL                 // ushort[2048][2816] = 11534336
#define ARR_OFF   145916160ULL                 // uint[64*64] arrival flags, 256B stride = 16384
// total 145932544 bytes (~139.2 MiB)

__device__ __forceinline__ unsigned short f2b(float f) {
  unsigned u = __float_as_uint(f);
  unsigned r = (u + 0x7fffu + ((u >> 16) & 1u)) >> 16;
  return (unsigned short)r;
}
__device__ __forceinline__ float b2f(unsigned short s) {
  return __uint_as_float(((unsigned)s) << 16);
}
__device__ __forceinline__ double sigm_d(double x) { return 1.0 / (1.0 + exp(-x)); }
__device__ __forceinline__ double tanh_d(double x) {
  double e = exp(2.0 * x);
  return isinf(e) ? 1.0 : (1.0 - 2.0 / (e + 1.0));
}

// ---------------- prep kernels ----------------
__global__ __launch_bounds__(256) void k_cvt2(const float* __restrict__ in,
                                              unsigned short* __restrict__ hi,
                                              unsigned short* __restrict__ lo, size_t n) {
  size_t i = (size_t)blockIdx.x * blockDim.x + threadIdx.x;
  size_t stride = (size_t)gridDim.x * blockDim.x;
  for (; i < n; i += stride) {
    float v = in[i];
    unsigned short h = f2b(v);
    hi[i] = h;
    lo[i] = f2b(v - b2f(h));
  }
}

__global__ __launch_bounds__(256) void k_wrec2(const float* __restrict__ Whh,
                                               const float* __restrict__ Wih,
                                               unsigned short* __restrict__ out) {
  size_t i = (size_t)blockIdx.x * 256 + threadIdx.x;   // over 2048*2816
  if (i >= (size_t)G_ * KW) return;
  int gb = (int)(i / KW), k = (int)(i % KW);
  int blk = gb >> 5, c = gb & 31;
  int grow = (c >> 3) * H_ + blk * JPB + (c & 7);      // gate*512 + hidden index
  unsigned short v;
  if (k < 512) {                                        // Whh hi
    v = f2b(Whh[(size_t)grow * 512 + k]);
  } else if (k < 1024) {                                // Whh lo
    float w = Whh[(size_t)grow * 512 + (k - 512)];
    v = f2b(w - b2f(f2b(w)));
  } else if (k < 1536) {                                // Wih-x hi
    v = f2b(Wih[(size_t)grow * 768 + (k - 1024)]);
  } else if (k < 2048) {                                // Wih-x lo
    float w = Wih[(size_t)grow * 768 + (k - 1536)];
    v = f2b(w - b2f(f2b(w)));
  } else if (k < 2304) {                                // Wih-hippo hi
    v = f2b(Wih[(size_t)grow * 768 + 512 + (k - 2048)]);
  } else if (k < 2560) {                                // Wih-hippo mid
    float w = Wih[(size_t)grow * 768 + 512 + (k - 2304)];
    v = f2b(w - b2f(f2b(w)));
  } else {                                              // Wih-hippo lo
    float w = Wih[(size_t)grow * 768 + 512 + (k - 2560)];
    float h1 = b2f(f2b(w));
    float m1 = b2f(f2b(w - h1));
    v = f2b(w - h1 - m1);
  }
  out[i] = v;
}

// ---------------- persistent sequential kernel ----------------
__global__ __launch_bounds__(256, 1) void k_seq(const unsigned short* __restrict__ XBH,
                                                const unsigned short* __restrict__ XBL,
                                                const unsigned short* __restrict__ WREC,
                                                const float* __restrict__ Wh2h,
                                                const float* __restrict__ bh2h,
                                                const float* __restrict__ bih,
                                                const float* __restrict__ bhh,
                                                float* __restrict__ out,
                                                unsigned short* __restrict__ HB,
                                                double* __restrict__ SfP,
                                                unsigned* __restrict__ arr) {
  const int blk = blockIdx.x, tid = threadIdx.x;

  __shared__ double hip_d[32][257];            // fp64 hippo state (padded)
  __shared__ unsigned short hip_hi[32][264];   // bf16 hi/mid/lo for MFMA A-frags
  __shared__ unsigned short hip_mi[32][264];
  __shared__ unsigned short hip_lo[32][264];
  __shared__ float gat_xh[32][33];             // x+h MFMA partial
  __shared__ float gat_n[32][33];              // hippo MFMA partial
  __shared__ double cst[32][JPB];              // cell state fp64
  __shared__ double segw[32][8], segu[32][8];
  __shared__ double sfl[32];
  __shared__ double wbar[JPB];
  __shared__ double stabd[256];
  __shared__ double sbeta;

  for (int i = tid; i < 32 * 257; i += 256) (&hip_d[0][0])[i] = 0.0;
  for (int i = tid; i < 32 * 264; i += 256) {
    (&hip_hi[0][0])[i] = 0; (&hip_mi[0][0])[i] = 0; (&hip_lo[0][0])[i] = 0;
  }
  for (int i = tid; i < 32 * JPB; i += 256) (&cst[0][0])[i] = 0.0;
  if (tid < 256) stabd[tid] = sqrt(2.0 * (double)tid + 1.0);
  if (tid < JPB) {
    double s = 0.0;
    for (int n = 0; n < NH_; ++n) s += (double)Wh2h[(size_t)n * H_ + blk * JPB + tid];
    wbar[tid] = s;
  }
  if (tid == 0) {
    double s = 0.0;
    for (int n = 0; n < NH_; ++n) s += (double)bh2h[n];
    sbeta = s;
  }
  __syncthreads();

  // MFMA roles (4 waves)
  const int w = tid >> 6, l = tid & 63;
  const int lb = l & 15, lq = l >> 4;
  const int mt = w & 1, nt = w >> 1;
  const int bA = mt * 16 + lb;         // batch row for A frags
  const int cB = nt * 16 + lb;         // local gate col for B frags
  const unsigned short* wrow = WREC + ((size_t)(blk * 32 + cB)) * KW + lq * 8;
  // elementwise roles
  const int eb = tid >> 3, ej = tid & 7;
  const int jg = blk * JPB + ej;
  // per-thread gate biases (fp64)
  const double bi0 = (double)bih[0 * 512 + jg] + (double)bhh[0 * 512 + jg];
  const double bi1 = (double)bih[1 * 512 + jg] + (double)bhh[1 * 512 + jg];
  const double bi2 = (double)bih[2 * 512 + jg] + (double)bhh[2 * 512 + jg];
  const double bi3 = (double)bih[3 * 512 + jg] + (double)bhh[3 * 512 + jg];
  // hippo-scan roles
  const int hb = tid & 31, hs = tid >> 5;

  // Hippo-path B fragments are loop-invariant: hoist into registers once
  // (24 short8 = 96 VGPR, live for all 2048 steps).
  short8 nB[24];
#pragma unroll
  for (int kt = 0; kt < 8; ++kt) {
    nB[kt * 3 + 0] = *(const short8*)(wrow + 2048 + kt * 32);
    nB[kt * 3 + 1] = *(const short8*)(wrow + 2304 + kt * 32);
    nB[kt * 3 + 2] = *(const short8*)(wrow + 2560 + kt * 32);
  }

  // x-path MFMA (Ootomo 3-pass, K=512); runs under the barrier wait for t+1
  auto xpass = [&](int tt) -> f32x4 {
    f32x4 a = {0.f, 0.f, 0.f, 0.f};
    const unsigned short* xh = XBH + ((size_t)bA * S_ + tt) * D_ + lq * 8;
    const unsigned short* xl = XBL + ((size_t)bA * S_ + tt) * D_ + lq * 8;
#pragma unroll
    for (int kt = 0; kt < 16; ++kt) {
      short8 ah = *(const short8*)(xh + kt * 32);
      short8 al = *(const short8*)(xl + kt * 32);
      short8 bh = *(const short8*)(wrow + 1024 + kt * 32);
      short8 bl = *(const short8*)(wrow + 1536 + kt * 32);
      a = __builtin_amdgcn_mfma_f32_16x16x32_bf16(ah, bh, a, 0, 0, 0);
      a = __builtin_amdgcn_mfma_f32_16x16x32_bf16(ah, bl, a, 0, 0, 0);
      a = __builtin_amdgcn_mfma_f32_16x16x32_bf16(al, bh, a, 0, 0, 0);
    }
    return a;
  };
  f32x4 axx = xpass(0);   // prologue: x-path for t=0

  for (int t = 0; t < S_; ++t) {
    const int wslot = t & 1, rslot = wslot ^ 1;

    // ---- gates MFMA ----
    // hippo path: hi/mid/lo x hi/mid/lo, 6 passes, K=256 (separate accumulator)
    f32x4 an = {0.f, 0.f, 0.f, 0.f};
#pragma unroll
    for (int kt = 0; kt < 8; ++kt) {
      short8 ah = *(const short8*)(&hip_hi[bA][kt * 32 + lq * 8]);
      short8 am = *(const short8*)(&hip_mi[bA][kt * 32 + lq * 8]);
      short8 al = *(const short8*)(&hip_lo[bA][kt * 32 + lq * 8]);
      an = __builtin_amdgcn_mfma_f32_16x16x32_bf16(ah, nB[kt * 3 + 0], an, 0, 0, 0);
      an = __builtin_amdgcn_mfma_f32_16x16x32_bf16(ah, nB[kt * 3 + 1], an, 0, 0, 0);
      an = __builtin_amdgcn_mfma_f32_16x16x32_bf16(am, nB[kt * 3 + 0], an, 0, 0, 0);
      an = __builtin_amdgcn_mfma_f32_16x16x32_bf16(ah, nB[kt * 3 + 2], an, 0, 0, 0);
      an = __builtin_amdgcn_mfma_f32_16x16x32_bf16(am, nB[kt * 3 + 1], an, 0, 0, 0);
      an = __builtin_amdgcn_mfma_f32_16x16x32_bf16(al, nB[kt * 3 + 0], an, 0, 0, 0);
    }
    // h path: hi/lo Ootomo 3-pass, K=512 (h from global double-buffer),
    // chained onto the prefetched x accumulator (order validated in R1: same absmax)
    f32x4 axh = axx;
    const unsigned short* hrow = HB + (size_t)rslot * (B_ * 1024) + (size_t)bA * 1024 + lq * 8;
#pragma unroll
    for (int kt = 0; kt < 16; ++kt) {
      short8 ah = *(const short8*)(hrow + kt * 32);
      short8 al = *(const short8*)(hrow + 512 + kt * 32);
      short8 bh = *(const short8*)(wrow + kt * 32);
      short8 bl = *(const short8*)(wrow + 512 + kt * 32);
      axh = __builtin_amdgcn_mfma_f32_16x16x32_bf16(ah, bh, axh, 0, 0, 0);
      axh = __builtin_amdgcn_mfma_f32_16x16x32_bf16(ah, bl, axh, 0, 0, 0);
      axh = __builtin_amdgcn_mfma_f32_16x16x32_bf16(al, bh, axh, 0, 0, 0);
    }
#pragma unroll
    for (int r = 0; r < 4; ++r) {
      gat_xh[mt * 16 + lq * 4 + r][cB] = axh[r];
      gat_n[mt * 16 + lq * 4 + r][cB] = an[r];
    }
    __syncthreads();

    // ---- elementwise LSTM (fp64) ----
    {
      double pi = (double)gat_xh[eb][0 * 8 + ej] + (double)gat_n[eb][0 * 8 + ej] + bi0;
      double pf = (double)gat_xh[eb][1 * 8 + ej] + (double)gat_n[eb][1 * 8 + ej] + bi1;
      double pg = (double)gat_xh[eb][2 * 8 + ej] + (double)gat_n[eb][2 * 8 + ej] + bi2;
      double po = (double)gat_xh[eb][3 * 8 + ej] + (double)gat_n[eb][3 * 8 + ej] + bi3;
      double c = sigm_d(pf) * cst[eb][ej] + sigm_d(pi) * tanh_d(pg);
      cst[eb][ej] = c;
      double h = sigm_d(po) * tanh_d(c);
      size_t oidx = (size_t)eb * (S_ * H_) + (size_t)t * H_ + jg;
      out[oidx] = (float)h;
      out[(size_t)B_ * S_ * H_ + oidx] = (float)c;
      float hf = (float)h;
      unsigned short hh = f2b(hf);
      unsigned short hl = f2b((float)(h - (double)b2f(hh)));
      unsigned short* hb_w = HB + (size_t)wslot * (B_ * 1024) + (size_t)eb * 1024;
      hb_w[jg] = hh;
      hb_w[512 + jg] = hl;
      // partial S_f (fp64)
      double part = h * wbar[ej];
      part += __shfl_down(part, 4, 64);
      part += __shfl_down(part, 2, 64);
      part += __shfl_down(part, 1, 64);
      if (ej == 0) SfP[(size_t)wslot * (NBLK * B_) + blk * B_ + eb] = part;
    }
    __syncthreads();   // drains vmem before barrier arrival

    if (t == S_ - 1) break;

    // -------- device barrier: per-block flags, no RMW, wave-parallel poll --------
    if (tid == 0)
      __hip_atomic_store(&arr[(size_t)blk * 64], (unsigned)(t + 1),
                         __ATOMIC_RELEASE, __HIP_MEMORY_SCOPE_AGENT);

    // ---- x-path MFMA for t+1, hidden under the barrier wait ----
    axx = xpass(t + 1);

    if (tid < 64) {
      unsigned* ap = arr + (size_t)tid * 64;
      const unsigned target = (unsigned)(t + 1);
      while (__hip_atomic_load(ap, __ATOMIC_RELAXED, __HIP_MEMORY_SCOPE_AGENT) < target) {}
      __threadfence();  // acquire: invalidate caches
    }
    __syncthreads();

    // S_f reduce (fp64) + hippo segment sums (fp64)
    {
      const double* sp = SfP + (size_t)wslot * (NBLK * B_) + eb;
      double v = 0.0;
#pragma unroll
      for (int m = 0; m < 8; ++m) v += sp[(ej * 8 + m) * B_];
      v += __shfl_down(v, 4, 64);
      v += __shfl_down(v, 2, 64);
      v += __shfl_down(v, 1, 64);
      if (ej == 0) sfl[eb] = v + sbeta;

      double sw = 0.0, su = 0.0;
#pragma unroll 4
      for (int i = 0; i < 32; ++i) {
        double hv = hip_d[hb][hs * 32 + i];
        sw += stabd[hs * 32 + i] * hv;
        su += hv;
      }
      segw[hb][hs] = sw;
      segu[hb][hs] = su;
    }
    __syncthreads();

    // hippo closed-form update in fp64 (redundant per block, deterministic)
    {
      double U = 0.0, Sh = 0.0;
#pragma unroll
      for (int s2 = 0; s2 < 8; ++s2) {
        Sh += segu[hb][s2];
        if (s2 < hs) U += segw[hb][s2];
      }
      const double Sf = sfl[hb];
      const double inv = 0.5 / (double)(t + 1);
      for (int i = 0; i < 32; ++i) {
        int n = hs * 32 + i;
        double hn = hip_d[hb][n];
        double v = Sh + inv * (stabd[n] * (Sf - U) - (double)(n + 1) * hn);
        v = fmin(fmax(v, -MAXS), MAXS);
        hip_d[hb][n] = v;
        unsigned short vh = f2b((float)v);
        double rem = v - (double)b2f(vh);
        unsigned short vm = f2b((float)rem);
        rem -= (double)b2f(vm);
        hip_hi[hb][n] = vh;
        hip_mi[hb][n] = vm;
        hip_lo[hb][n] = f2b((float)rem);
        U += stabd[n] * hn;
      }
    }
    __syncthreads();
  }
}

extern "C" void kernel_launch(void* const* d_in, const int* in_sizes, int n_in,
                              void* d_out, int out_size, void* d_ws, size_t ws_size,
                              hipStream_t stream) {
  const float* x    = (const float*)d_in[0];
  const float* Wih  = (const float*)d_in[1];
  const float* Whh  = (const float*)d_in[2];
  const float* bih  = (const float*)d_in[3];
  const float* bhh  = (const float*)d_in[4];
  const float* Wh2h = (const float*)d_in[5];
  const float* bh2h = (const float*)d_in[6];
  float* out = (float*)d_out;
  char* ws = (char*)d_ws;

  double* SfP          = (double*)(ws + SFP_OFF);
  unsigned short* HB   = (unsigned short*)(ws + HB_OFF);
  unsigned short* XBH  = (unsigned short*)(ws + XBH_OFF);
  unsigned short* XBL  = (unsigned short*)(ws + XBL_OFF);
  unsigned short* WREC = (unsigned short*)(ws + WREC_OFF);
  unsigned* arr        = (unsigned*)(ws + ARR_OFF);

  hipMemsetAsync(ws, 0, STATE_BYTES, stream);
  hipMemsetAsync(ws + ARR_OFF, 0, 16384, stream);
  k_cvt2<<<8192, 256, 0, stream>>>(x, XBH, XBL, (size_t)B_ * S_ * D_);
  k_wrec2<<<((size_t)G_ * KW + 255) / 256, 256, 0, stream>>>(Whh, Wih, WREC);
  k_seq<<<NBLK, 256, 0, stream>>>(XBH, XBL, WREC, Wh2h, bh2h, bih, bhh, out, HB, SfP, arr);
}

// Round 3
// 47897.235 us; speedup vs baseline: 1.3671x; 1.0904x over previous
//
#include <hip/hip_runtime.h>

// ---------------------------------------------------------------------------
// HiPPO-LSTM, B=32, S=2048, D=512, H=512, N=256, G=2048.
//
// Fully-fused sequential kernel (64 persistent blocks, 1 device barrier/step):
//   gates = x_t·Wx^T + h·Whh^T + hippo·Wn^T   (all via bf16 MFMA, split ops:
//     x,h paths: hi/lo Ootomo 3-pass; hippo path: hi/mid/lo 6-pass)
//   elementwise LSTM in fp64; S_f[b] = h·wbar + beta in fp64
//   barrier; closed-form fp64 hippo update.
//
// R6 (kill the per-step coherence machinery — R2 still spent ~20µs/step in
// fence/inv + post-inv L3 refetch bursts):
//   * NO __threadfence, NO release-wbl2. All cross-block data (HB h-plane,
//     SfP partials, arrival flags) accessed ONLY via relaxed AGENT atomics
//     (sc1: bypass L2, coherent at L3). L2 never caches exchange lines ->
//     never stale -> no invalidate needed -> WREC weights + x stream stay
//     L2-resident across all 2048 steps.
//   * Flag store RELAXED: the vmcnt(0) the compiler emits before the
//     preceding __syncthreads guarantees all sc1 data stores are L3-acked
//     before any lane reaches the flag store. No wbl2 scan.
//   * h-plane prefetch: 64x 8B relaxed atomic loads (global_load_dwordx2
//     sc1, compiler-managed waits, spill-safe) issued BEFORE the hippo
//     MFMA chain, consumed after -> L3 latency hidden under MFMA.
//     (R1's mistake: scalar atomic loads + LDS round-trip serialized this.)
//   * hippo segment sums moved under the barrier wait (depend only on
//     last step's update) -> shorter post-barrier critical path.
//   * out[] nontemporal stores (keep L2 clean, stop thrashing x in L3).
//   Kept from R2: flag-array barrier (no RMW, wave-parallel poll),
//   x-path MFMA under barrier wait, hippo-weight frags parked in regs.
// ---------------------------------------------------------------------------

#define B_ 32
#define S_ 2048
#define D_ 512
#define H_ 512
#define NH_ 256
#define G_ 2048
#define KW 2816          // WREC row: hh_hi 512|hh_lo 512|xw_hi 512|xw_lo 512|nw_hi 256|nw_mid 256|nw_lo 256
#define NBLK 64
#define JPB 8
#define MAXS 1000.0

typedef __attribute__((ext_vector_type(8))) short short8;
typedef __attribute__((ext_vector_type(4))) float f32x4;

// ws layout (bytes)
#define CNT_OFF   0ULL
#define SFP_OFF   256ULL                       // double[2][64][32] = 32768
#define HB_OFF    33024ULL                     // ushort[2][32][1024] = 131072 (hi|lo planes)
#define STATE_BYTES 164096ULL
#define XBH_OFF   164096ULL                    // ushort[32][2048][512] = 67108864
#define XBL_OFF   67272960ULL                  // ushort[32][2048][512] = 67108864
#define WREC_OFF  134381824ULL                 // ushort[2048][2816] = 11534336
#define ARR_OFF   145916160ULL                 // uint[64*64] arrival flags, 256B stride = 16384
// total 145932544 bytes (~139.2 MiB)

#define AL(p)    __hip_atomic_load((p), __ATOMIC_RELAXED, __HIP_MEMORY_SCOPE_AGENT)
#define AS(p, v) __hip_atomic_store((p), (v), __ATOMIC_RELAXED, __HIP_MEMORY_SCOPE_AGENT)

__device__ __forceinline__ unsigned short f2b(float f) {
  unsigned u = __float_as_uint(f);
  unsigned r = (u + 0x7fffu + ((u >> 16) & 1u)) >> 16;
  return (unsigned short)r;
}
__device__ __forceinline__ float b2f(unsigned short s) {
  return __uint_as_float(((unsigned)s) << 16);
}
__device__ __forceinline__ double sigm_d(double x) { return 1.0 / (1.0 + exp(-x)); }
__device__ __forceinline__ double tanh_d(double x) {
  double e = exp(2.0 * x);
  return isinf(e) ? 1.0 : (1.0 - 2.0 / (e + 1.0));
}
__device__ __forceinline__ short8 mk8(unsigned long long a, unsigned long long b) {
  union { unsigned long long q[2]; short8 s; } u;
  u.q[0] = a; u.q[1] = b;
  return u.s;
}

// ---------------- prep kernels ----------------
__global__ __launch_bounds__(256) void k_cvt2(const float* __restrict__ in,
                                              unsigned short* __restrict__ hi,
                                              unsigned short* __restrict__ lo, size_t n) {
  size_t i = (size_t)blockIdx.x * blockDim.x + threadIdx.x;
  size_t stride = (size_t)gridDim.x * blockDim.x;
  for (; i < n; i += stride) {
    float v = in[i];
    unsigned short h = f2b(v);
    hi[i] = h;
    lo[i] = f2b(v - b2f(h));
  }
}

__global__ __launch_bounds__(256) void k_wrec2(const float* __restrict__ Whh,
                                               const float* __restrict__ Wih,
                                               unsigned short* __restrict__ out) {
  size_t i = (size_t)blockIdx.x * 256 + threadIdx.x;   // over 2048*2816
  if (i >= (size_t)G_ * KW) return;
  int gb = (int)(i / KW), k = (int)(i % KW);
  int blk = gb >> 5, c = gb & 31;
  int grow = (c >> 3) * H_ + blk * JPB + (c & 7);      // gate*512 + hidden index
  unsigned short v;
  if (k < 512) {                                        // Whh hi
    v = f2b(Whh[(size_t)grow * 512 + k]);
  } else if (k < 1024) {                                // Whh lo
    float w = Whh[(size_t)grow * 512 + (k - 512)];
    v = f2b(w - b2f(f2b(w)));
  } else if (k < 1536) {                                // Wih-x hi
    v = f2b(Wih[(size_t)grow * 768 + (k - 1024)]);
  } else if (k < 2048) {                                // Wih-x lo
    float w = Wih[(size_t)grow * 768 + (k - 1536)];
    v = f2b(w - b2f(f2b(w)));
  } else if (k < 2304) {                                // Wih-hippo hi
    v = f2b(Wih[(size_t)grow * 768 + 512 + (k - 2048)]);
  } else if (k < 2560) {                                // Wih-hippo mid
    float w = Wih[(size_t)grow * 768 + 512 + (k - 2304)];
    v = f2b(w - b2f(f2b(w)));
  } else {                                              // Wih-hippo lo
    float w = Wih[(size_t)grow * 768 + 512 + (k - 2560)];
    float h1 = b2f(f2b(w));
    float m1 = b2f(f2b(w - h1));
    v = f2b(w - h1 - m1);
  }
  out[i] = v;
}

// ---------------- persistent sequential kernel ----------------
__global__ __launch_bounds__(256, 1) void k_seq(const unsigned short* __restrict__ XBH,
                                                const unsigned short* __restrict__ XBL,
                                                const unsigned short* __restrict__ WREC,
                                                const float* __restrict__ Wh2h,
                                                const float* __restrict__ bh2h,
                                                const float* __restrict__ bih,
                                                const float* __restrict__ bhh,
                                                float* __restrict__ out,
                                                unsigned short* __restrict__ HB,
                                                double* __restrict__ SfP,
                                                unsigned* __restrict__ arr) {
  const int blk = blockIdx.x, tid = threadIdx.x;

  __shared__ double hip_d[32][257];            // fp64 hippo state (padded)
  __shared__ unsigned short hip_hi[32][264];   // bf16 hi/mid/lo for MFMA A-frags
  __shared__ unsigned short hip_mi[32][264];
  __shared__ unsigned short hip_lo[32][264];
  __shared__ float gat_xh[32][33];             // x+h MFMA partial
  __shared__ float gat_n[32][33];              // hippo MFMA partial
  __shared__ double cst[32][JPB];              // cell state fp64
  __shared__ double segw[32][8], segu[32][8];
  __shared__ double sfl[32];
  __shared__ double wbar[JPB];
  __shared__ double stabd[256];
  __shared__ double sbeta;

  for (int i = tid; i < 32 * 257; i += 256) (&hip_d[0][0])[i] = 0.0;
  for (int i = tid; i < 32 * 264; i += 256) {
    (&hip_hi[0][0])[i] = 0; (&hip_mi[0][0])[i] = 0; (&hip_lo[0][0])[i] = 0;
  }
  for (int i = tid; i < 32 * JPB; i += 256) (&cst[0][0])[i] = 0.0;
  if (tid < 256) stabd[tid] = sqrt(2.0 * (double)tid + 1.0);
  if (tid < JPB) {
    double s = 0.0;
    for (int n = 0; n < NH_; ++n) s += (double)Wh2h[(size_t)n * H_ + blk * JPB + tid];
    wbar[tid] = s;
  }
  if (tid == 0) {
    double s = 0.0;
    for (int n = 0; n < NH_; ++n) s += (double)bh2h[n];
    sbeta = s;
  }
  __syncthreads();

  // MFMA roles (4 waves)
  const int w = tid >> 6, l = tid & 63;
  const int lb = l & 15, lq = l >> 4;
  const int mt = w & 1, nt = w >> 1;
  const int bA = mt * 16 + lb;         // batch row for A frags
  const int cB = nt * 16 + lb;         // local gate col for B frags
  const unsigned short* wrow = WREC + ((size_t)(blk * 32 + cB)) * KW + lq * 8;
  // elementwise roles
  const int eb = tid >> 3, ej = tid & 7;
  const int jg = blk * JPB + ej;
  // per-thread gate biases (fp64)
  const double bi0 = (double)bih[0 * 512 + jg] + (double)bhh[0 * 512 + jg];
  const double bi1 = (double)bih[1 * 512 + jg] + (double)bhh[1 * 512 + jg];
  const double bi2 = (double)bih[2 * 512 + jg] + (double)bhh[2 * 512 + jg];
  const double bi3 = (double)bih[3 * 512 + jg] + (double)bhh[3 * 512 + jg];
  // hippo-scan roles
  const int hb = tid & 31, hs = tid >> 5;

  // Hippo-path B fragments are loop-invariant: hoist into registers once
  // (24 short8 = 96 VGPR, live for all 2048 steps).
  short8 nB[24];
#pragma unroll
  for (int kt = 0; kt < 8; ++kt) {
    nB[kt * 3 + 0] = *(const short8*)(wrow + 2048 + kt * 32);
    nB[kt * 3 + 1] = *(const short8*)(wrow + 2304 + kt * 32);
    nB[kt * 3 + 2] = *(const short8*)(wrow + 2560 + kt * 32);
  }

  // x-path MFMA (Ootomo 3-pass, K=512); runs under the barrier wait for t+1
  auto xpass = [&](int tt) -> f32x4 {
    f32x4 a = {0.f, 0.f, 0.f, 0.f};
    const unsigned short* xh = XBH + ((size_t)bA * S_ + tt) * D_ + lq * 8;
    const unsigned short* xl = XBL + ((size_t)bA * S_ + tt) * D_ + lq * 8;
#pragma unroll
    for (int kt = 0; kt < 16; ++kt) {
      short8 ah = *(const short8*)(xh + kt * 32);
      short8 al = *(const short8*)(xl + kt * 32);
      short8 bh = *(const short8*)(wrow + 1024 + kt * 32);
      short8 bl = *(const short8*)(wrow + 1536 + kt * 32);
      a = __builtin_amdgcn_mfma_f32_16x16x32_bf16(ah, bh, a, 0, 0, 0);
      a = __builtin_amdgcn_mfma_f32_16x16x32_bf16(ah, bl, a, 0, 0, 0);
      a = __builtin_amdgcn_mfma_f32_16x16x32_bf16(al, bh, a, 0, 0, 0);
    }
    return a;
  };
  f32x4 axx = xpass(0);   // prologue: x-path for t=0

  for (int t = 0; t < S_; ++t) {
    const int wslot = t & 1, rslot = wslot ^ 1;

    // ---- h-plane prefetch: 64x 8B sc1 loads, issued before hippo MFMA ----
    // (HB lines are only ever touched with sc1 -> never in L2 -> never stale)
    const unsigned long long* hq =
        (const unsigned long long*)(HB + (size_t)rslot * (B_ * 1024) + (size_t)bA * 1024 + lq * 8);
    unsigned long long hA[64];
#pragma unroll
    for (int kt = 0; kt < 16; ++kt) {
      hA[kt * 2 + 0]      = AL(hq + kt * 8 + 0);        // hi plane, ushorts [kt*32 .. +4)
      hA[kt * 2 + 1]      = AL(hq + kt * 8 + 1);        // hi plane, ushorts [kt*32+4 .. +8)
      hA[32 + kt * 2 + 0] = AL(hq + 128 + kt * 8 + 0);  // lo plane (+512 ushort = +128 qw)
      hA[32 + kt * 2 + 1] = AL(hq + 128 + kt * 8 + 1);
    }

    // ---- gates MFMA ----
    // hippo path: hi/mid/lo x hi/mid/lo, 6 passes, K=256 (separate accumulator)
    f32x4 an = {0.f, 0.f, 0.f, 0.f};
#pragma unroll
    for (int kt = 0; kt < 8; ++kt) {
      short8 ah = *(const short8*)(&hip_hi[bA][kt * 32 + lq * 8]);
      short8 am = *(const short8*)(&hip_mi[bA][kt * 32 + lq * 8]);
      short8 al = *(const short8*)(&hip_lo[bA][kt * 32 + lq * 8]);
      an = __builtin_amdgcn_mfma_f32_16x16x32_bf16(ah, nB[kt * 3 + 0], an, 0, 0, 0);
      an = __builtin_amdgcn_mfma_f32_16x16x32_bf16(ah, nB[kt * 3 + 1], an, 0, 0, 0);
      an = __builtin_amdgcn_mfma_f32_16x16x32_bf16(am, nB[kt * 3 + 0], an, 0, 0, 0);
      an = __builtin_amdgcn_mfma_f32_16x16x32_bf16(ah, nB[kt * 3 + 2], an, 0, 0, 0);
      an = __builtin_amdgcn_mfma_f32_16x16x32_bf16(am, nB[kt * 3 + 1], an, 0, 0, 0);
      an = __builtin_amdgcn_mfma_f32_16x16x32_bf16(al, nB[kt * 3 + 0], an, 0, 0, 0);
    }
    // h path: hi/lo Ootomo 3-pass, K=512 (A-frags from prefetched regs),
    // chained onto the prefetched x accumulator (order validated: same absmax)
    f32x4 axh = axx;
#pragma unroll
    for (int kt = 0; kt < 16; ++kt) {
      short8 ah = mk8(hA[kt * 2 + 0], hA[kt * 2 + 1]);
      short8 al = mk8(hA[32 + kt * 2 + 0], hA[32 + kt * 2 + 1]);
      short8 bh = *(const short8*)(wrow + kt * 32);
      short8 bl = *(const short8*)(wrow + 512 + kt * 32);
      axh = __builtin_amdgcn_mfma_f32_16x16x32_bf16(ah, bh, axh, 0, 0, 0);
      axh = __builtin_amdgcn_mfma_f32_16x16x32_bf16(ah, bl, axh, 0, 0, 0);
      axh = __builtin_amdgcn_mfma_f32_16x16x32_bf16(al, bh, axh, 0, 0, 0);
    }
#pragma unroll
    for (int r = 0; r < 4; ++r) {
      gat_xh[mt * 16 + lq * 4 + r][cB] = axh[r];
      gat_n[mt * 16 + lq * 4 + r][cB] = an[r];
    }
    __syncthreads();

    // ---- elementwise LSTM (fp64) ----
    {
      double pi = (double)gat_xh[eb][0 * 8 + ej] + (double)gat_n[eb][0 * 8 + ej] + bi0;
      double pf = (double)gat_xh[eb][1 * 8 + ej] + (double)gat_n[eb][1 * 8 + ej] + bi1;
      double pg = (double)gat_xh[eb][2 * 8 + ej] + (double)gat_n[eb][2 * 8 + ej] + bi2;
      double po = (double)gat_xh[eb][3 * 8 + ej] + (double)gat_n[eb][3 * 8 + ej] + bi3;
      double c = sigm_d(pf) * cst[eb][ej] + sigm_d(pi) * tanh_d(pg);
      cst[eb][ej] = c;
      double h = sigm_d(po) * tanh_d(c);
      size_t oidx = (size_t)eb * (S_ * H_) + (size_t)t * H_ + jg;
      __builtin_nontemporal_store((float)h, &out[oidx]);
      __builtin_nontemporal_store((float)c, &out[(size_t)B_ * S_ * H_ + oidx]);
      float hf = (float)h;
      unsigned short hh = f2b(hf);
      unsigned short hl = f2b((float)(h - (double)b2f(hh)));
      unsigned short* hb_w = HB + (size_t)wslot * (B_ * 1024) + (size_t)eb * 1024;
      AS(hb_w + jg, hh);
      AS(hb_w + 512 + jg, hl);
      // partial S_f (fp64)
      double part = h * wbar[ej];
      part += __shfl_down(part, 4, 64);
      part += __shfl_down(part, 2, 64);
      part += __shfl_down(part, 1, 64);
      if (ej == 0) AS(SfP + (size_t)wslot * (NBLK * B_) + blk * B_ + eb, part);
    }
    __syncthreads();   // compiler emits vmcnt(0): all sc1 stores L3-acked here

    if (t == S_ - 1) break;

    // -------- device barrier: per-block flags, RELAXED store (no wbl2) --------
    if (tid == 0) AS(&arr[(size_t)blk * 64], (unsigned)(t + 1));

    // ---- x-path MFMA for t+1, hidden under the barrier wait ----
    axx = xpass(t + 1);

    // ---- hippo segment sums (depend only on last step's update) ----
    {
      double sw = 0.0, su = 0.0;
#pragma unroll 4
      for (int i = 0; i < 32; ++i) {
        double hv = hip_d[hb][hs * 32 + i];
        sw += stabd[hs * 32 + i] * hv;
        su += hv;
      }
      segw[hb][hs] = sw;
      segu[hb][hs] = su;
    }

    if (tid < 64) {
      unsigned* ap = arr + (size_t)tid * 64;
      const unsigned target = (unsigned)(t + 1);
      while (AL(ap) < target) {}
    }
    __syncthreads();

    // ---- S_f reduce (fp64, sc1 loads) ----
    {
      const double* sp = SfP + (size_t)wslot * (NBLK * B_) + eb;
      double v = 0.0;
#pragma unroll
      for (int m = 0; m < 8; ++m) v += AL(sp + (size_t)(ej * 8 + m) * B_);
      v += __shfl_down(v, 4, 64);
      v += __shfl_down(v, 2, 64);
      v += __shfl_down(v, 1, 64);
      if (ej == 0) sfl[eb] = v + sbeta;
    }
    __syncthreads();

    // hippo closed-form update in fp64 (redundant per block, deterministic)
    {
      double U = 0.0, Sh = 0.0;
#pragma unroll
      for (int s2 = 0; s2 < 8; ++s2) {
        Sh += segu[hb][s2];
        if (s2 < hs) U += segw[hb][s2];
      }
      const double Sf = sfl[hb];
      const double inv = 0.5 / (double)(t + 1);
      for (int i = 0; i < 32; ++i) {
        int n = hs * 32 + i;
        double hn = hip_d[hb][n];
        double v = Sh + inv * (stabd[n] * (Sf - U) - (double)(n + 1) * hn);
        v = fmin(fmax(v, -MAXS), MAXS);
        hip_d[hb][n] = v;
        unsigned short vh = f2b((float)v);
        double rem = v - (double)b2f(vh);
        unsigned short vm = f2b((float)rem);
        rem -= (double)b2f(vm);
        hip_hi[hb][n] = vh;
        hip_mi[hb][n] = vm;
        hip_lo[hb][n] = f2b((float)rem);
        U += stabd[n] * hn;
      }
    }
    __syncthreads();
  }
}

extern "C" void kernel_launch(void* const* d_in, const int* in_sizes, int n_in,
                              void* d_out, int out_size, void* d_ws, size_t ws_size,
                              hipStream_t stream) {
  const float* x    = (const float*)d_in[0];
  const float* Wih  = (const float*)d_in[1];
  const float* Whh  = (const float*)d_in[2];
  const float* bih  = (const float*)d_in[3];
  const float* bhh  = (const float*)d_in[4];
  const float* Wh2h = (const float*)d_in[5];
  const float* bh2h = (const float*)d_in[6];
  float* out = (float*)d_out;
  char* ws = (char*)d_ws;

  double* SfP          = (double*)(ws + SFP_OFF);
  unsigned short* HB   = (unsigned short*)(ws + HB_OFF);
  unsigned short* XBH  = (unsigned short*)(ws + XBH_OFF);
  unsigned short* XBL  = (unsigned short*)(ws + XBL_OFF);
  unsigned short* WREC = (unsigned short*)(ws + WREC_OFF);
  unsigned* arr        = (unsigned*)(ws + ARR_OFF);

  hipMemsetAsync(ws, 0, STATE_BYTES, stream);
  hipMemsetAsync(ws + ARR_OFF, 0, 16384, stream);
  k_cvt2<<<8192, 256, 0, stream>>>(x, XBH, XBL, (size_t)B_ * S_ * D_);
  k_wrec2<<<((size_t)G_ * KW + 255) / 256, 256, 0, stream>>>(Whh, Wih, WREC);
  k_seq<<<NBLK, 256, 0, stream>>>(XBH, XBL, WREC, Wh2h, bh2h, bih, bhh, out, HB, SfP, arr);
}